// Round 6
// baseline (134.321 us; speedup 1.0000x reference)
//
#include <hip/hip_runtime.h>
#include <math.h>

// HMM forward: chunked warm-start + per-step MFMA GEMM, A register-resident fp8.
// B=32, T=2048, S=512, E=32. WG = one time-chunk (L=8 logged, WARM=4 from
// uniform; chunk 0 uses exact pi-init). 256 threads = 4 waves, 1 wave/SIMD,
// full 512-reg budget: areg (A^T slice, 128 i64 = 256 regs) + acc 64 + em 16
// leaves ~130 regs for the compiler to prefetch all LDS B-reads per step.
// mfma_f32_32x32x16_fp8_fp8: D'[n][m] = sum_k A[k][n]*alpha[m][k];
// C/D col = batch m = lane&31 (zi needs no shuffle), row n per reg.
// Scaling: A x128, alpha x256, z' = 32768*z; one logf after the loop.

#define BATCH 32
#define T_LEN 2048
#define S_N   512
#define E_N   32
#define CHUNKS 256
#define L_CH  (T_LEN / CHUNKS)   // 8
#define WARM  4
#define WIN   (L_CH + WARM)      // 12
#define ASTRIDE 520              // alpha row stride in BYTES (8-aligned, 2-way banks)
#define SA 256.0f
#define SM 128.0f

typedef __attribute__((ext_vector_type(16))) float floatx16;
typedef __attribute__((ext_vector_type(4))) short short4v;
typedef long long i64;

__device__ __forceinline__ float bf16_to_f(short s) {
    unsigned int u = ((unsigned int)(unsigned short)s) << 16;
    return __builtin_bit_cast(float, u);
}
__device__ __forceinline__ short f_to_bf16(float f) {
    unsigned int u = __builtin_bit_cast(unsigned int, f);
    u = (u + 0x7FFFu + ((u >> 16) & 1u)) >> 16;   // RNE
    return (short)u;
}

// ---------------- prep: A^T fp8 fragments (coalesced) + bf16 em table + out zero ----------------
// Aperm flat idx ((nb*32 + ks)*64 + lane), i64 of 8 fp8:
//   byte j = e4m3( A[ks*16 + (lane>>5)*8 + j][nb*32 + (lane&31)] * SM )
__global__ __launch_bounds__(256) void prep_kernel(
    const float* __restrict__ A, const float* __restrict__ Bem,
    i64* __restrict__ Aperm, short* __restrict__ emTg, float* __restrict__ out)
{
    __shared__ float s_A[16 * 512];   // one 16-row k-slab of A, 32 KB
    const int g = blockIdx.x, tid = threadIdx.x;
    if (g < 32) {
        const float* src = A + (size_t)g * 16 * 512;
#pragma unroll
        for (int p = 0; p < 8; ++p) {
            int idx = tid + 256 * p;
            *(float4*)&s_A[idx * 4] = *(const float4*)(src + idx * 4);
        }
        __syncthreads();
        const int lane_o = tid & 63;
        const int h = lane_o >> 5, mm = lane_o & 31;
#pragma unroll
        for (int p = 0; p < 4; ++p) {
            int nb = (tid >> 6) + 4 * p;
            int n = nb * 32 + mm;
            float f[8];
#pragma unroll
            for (int j = 0; j < 8; ++j)
                f[j] = s_A[(h * 8 + j) * 512 + n] * SM;
            int lo = __builtin_amdgcn_cvt_pk_fp8_f32(f[0], f[1], 0, 0);
            lo     = __builtin_amdgcn_cvt_pk_fp8_f32(f[2], f[3], lo, 1);
            int hi = __builtin_amdgcn_cvt_pk_fp8_f32(f[4], f[5], 0, 0);
            hi     = __builtin_amdgcn_cvt_pk_fp8_f32(f[6], f[7], hi, 1);
            Aperm[(size_t)(nb * 32 + g) * 64 + lane_o] =
                (i64)(unsigned int)lo | ((i64)(unsigned int)hi << 32);
        }
    } else {
#pragma unroll
        for (int p = 0; p < 64; ++p) {
            int idx = tid + 256 * p;             // 0..16383
            int e = idx >> 9, n = idx & 511;
            emTg[idx] = f_to_bf16(Bem[n * E_N + e]);
        }
        if (tid < 32) out[tid] = 0.0f;
    }
}

// ---------------- main kernel ----------------

__global__ __launch_bounds__(256, 1) void hmm_kernel(
    const float* __restrict__ inputs, const i64* __restrict__ Aperm,
    const float* __restrict__ pi, const short* __restrict__ emTg,
    float* __restrict__ out)
{
    __shared__ i64  s_alpha8[BATCH * ASTRIDE / 8];   // fp8 alpha [m][k], 16.6 KB
    __shared__ float s_part[4][32];
    __shared__ float s_zi[32];
    __shared__ int   s_obs[BATCH * WIN];
    unsigned char* s_alpha = (unsigned char*)s_alpha8;

    const int c    = blockIdx.x;
    const int tid  = threadIdx.x;      // 0..255
    const int wv   = tid >> 6;         // wave 0..3 -> n-block of 128
    const int lane = tid & 63;
    const int h    = lane >> 5;        // half-wave (k-halves / row offset 4h)
    const int m    = lane & 31;        // batch column

    const int t_log = c * L_CH;
    const int t_end = t_log + L_CH;
    const int t_w0  = t_end - WIN;                 // may be negative
    int t0 = t_log - 1 - WARM;
    const bool exact0 = (t0 < 0);
    const int t_begin = (t0 < 0 ? 0 : t0) + 1;

    // ---- decode obs window from one-hot ----
    for (int i = tid; i < BATCH * WIN; i += 256) {
        int mm = i / WIN, tt = i - mm * WIN;
        int t = t_w0 + tt;
        if (t >= 0) {
            const float* p = inputs + ((size_t)mm * T_LEN + t) * E_N;
            float o = 0.0f;
#pragma unroll
            for (int gg = 0; gg < 8; ++gg) {
                float4 v = *(const float4*)(p + gg * 4);
                o += (4 * gg) * v.x + (4 * gg + 1) * v.y + (4 * gg + 2) * v.z + (4 * gg + 3) * v.w;
            }
            s_obs[i] = (int)(o + 0.5f);
        }
    }

    // ---- this wave's A^T slice: 128 i64 = 256 VGPRs, loaded once ----
    i64 areg[128];   // [tt*32 + ks]
#pragma unroll
    for (int i = 0; i < 128; ++i)
        areg[i] = Aperm[(size_t)(wv * 128 + i) * 64 + lane];
    __syncthreads();   // s_obs visible

    float logacc = 0.0f;   // tid < 32
    float zprod  = 1.0f;

    if (exact0) {
        // exact init (c==0): thread owns states j=tid, j=tid+256
        const int dt0 = -t_w0;
        float pj0 = pi[tid], pj1 = pi[tid + 256];
        for (int mm = 0; mm < 32; ++mm) {
            int o = s_obs[mm * WIN + dt0];
            float v = pj0 * bf16_to_f(emTg[o * S_N + tid]) +
                      pj1 * bf16_to_f(emTg[o * S_N + tid + 256]);
            v += __shfl_xor(v, 1);  v += __shfl_xor(v, 2);  v += __shfl_xor(v, 4);
            v += __shfl_xor(v, 8);  v += __shfl_xor(v, 16); v += __shfl_xor(v, 32);
            if (lane == 0) s_part[wv][mm] = v;
        }
        __syncthreads();
        if (tid < 32) {
            float z = s_part[0][tid] + s_part[1][tid] + s_part[2][tid] + s_part[3][tid];
            logacc += logf(z);                    // z0
            s_zi[tid] = SA / z;
        }
        __syncthreads();
        for (int mm = 0; mm < 32; ++mm) {
            int o = s_obs[mm * WIN + dt0];
            float zi = s_zi[mm];
            float v0 = pj0 * bf16_to_f(emTg[o * S_N + tid]) * zi;
            float v1 = pj1 * bf16_to_f(emTg[o * S_N + tid + 256]) * zi;
            s_alpha[mm * ASTRIDE + tid] =
                (unsigned char)(__builtin_amdgcn_cvt_pk_fp8_f32(v0, 0.0f, 0, 0) & 0xff);
            s_alpha[mm * ASTRIDE + tid + 256] =
                (unsigned char)(__builtin_amdgcn_cvt_pk_fp8_f32(v1, 0.0f, 0, 0) & 0xff);
        }
        __syncthreads();
    } else {
        // uniform warm start: alpha = 1/512 -> x256 = 0.5 -> e4m3 0x30
        const i64 u8 = 0x3030303030303030LL;
        for (int i = tid; i < BATCH * ASTRIDE / 8; i += 256) s_alpha8[i] = u8;
        __syncthreads();
    }

    // ---------------- time loop ----------------
    for (int t = t_begin; t < t_end; ++t) {
        const int dtw = t - t_w0;
        const int o = s_obs[m * WIN + dtw];                  // batch m's symbol
        const short* emp = emTg + o * S_N + wv * 128 + h * 4;
        short4v emv[4][4];                                    // [tt][grp]
#pragma unroll
        for (int tt = 0; tt < 4; ++tt)
#pragma unroll
            for (int gg = 0; gg < 4; ++gg)
                emv[tt][gg] = *(const short4v*)(emp + tt * 32 + gg * 8);

        floatx16 acc[4];
#pragma unroll
        for (int tt = 0; tt < 4; ++tt) acc[tt] = (floatx16)(0.0f);

#pragma unroll
        for (int ks = 0; ks < 32; ++ks) {
            i64 b = *(const i64*)(s_alpha + m * ASTRIDE + ks * 16 + h * 8);
#pragma unroll
            for (int tt = 0; tt < 4; ++tt)
                acc[tt] = __builtin_amdgcn_mfma_f32_32x32x16_fp8_fp8(areg[tt * 32 + ks], b, acc[tt], 0, 0, 0);
        }

        // emission scale + per-batch partial (row n = wv*128+tt*32+4h+(reg&3)+8*(reg>>2))
        float psum = 0.0f;
#pragma unroll
        for (int tt = 0; tt < 4; ++tt)
#pragma unroll
            for (int reg = 0; reg < 16; ++reg) {
                float v = acc[tt][reg] * bf16_to_f(emv[tt][reg >> 2][reg & 3]);
                acc[tt][reg] = v;
                psum += v;
            }
        psum += __shfl_xor(psum, 32);
        if (lane < 32) s_part[wv][m] = psum;
        __syncthreads();

        float zin = s_part[0][m] + s_part[1][m] + s_part[2][m] + s_part[3][m];
        if (t >= t_log) zprod *= zin * 0x1p-15f;   // z'/32768; logf deferred
        float zi = SA / zin;                        // col m = this lane's batch

        // normalize + pack fp8 + write next alpha (16 x ds_write_b32)
#pragma unroll
        for (int tt = 0; tt < 4; ++tt)
#pragma unroll
            for (int gg = 0; gg < 4; ++gg) {
                int pk = __builtin_amdgcn_cvt_pk_fp8_f32(acc[tt][gg * 4] * zi, acc[tt][gg * 4 + 1] * zi, 0, 0);
                pk     = __builtin_amdgcn_cvt_pk_fp8_f32(acc[tt][gg * 4 + 2] * zi, acc[tt][gg * 4 + 3] * zi, pk, 1);
                *(int*)(s_alpha + m * ASTRIDE + wv * 128 + tt * 32 + gg * 8 + h * 4) = pk;
            }
        __syncthreads();
    }

    if (tid < 32) atomicAdd(out + tid, logacc + logf(zprod));
}

// ---------------- launch ----------------

extern "C" void kernel_launch(void* const* d_in, const int* in_sizes, int n_in,
                              void* d_out, int out_size, void* d_ws, size_t ws_size,
                              hipStream_t stream) {
    const float* inputs = (const float*)d_in[0];   // [B,T,E] one-hot fp32
    const float* A      = (const float*)d_in[1];   // [S,S]
    const float* Bem    = (const float*)d_in[2];   // [S,E]
    const float* pi     = (const float*)d_in[3];   // [S]
    float* out = (float*)d_out;                    // [B]

    // workspace: Aperm fp8 256 KB | emTg bf16 32 KB
    i64*   Aperm = (i64*)d_ws;
    short* emTg  = (short*)((char*)d_ws + 256 * 1024);

    prep_kernel<<<33, 256, 0, stream>>>(A, Bem, Aperm, emTg, out);
    hmm_kernel<<<CHUNKS, 256, 0, stream>>>(inputs, Aperm, pi, emTg, out);
}

// Round 7
// 105.337 us; speedup vs baseline: 1.2752x; 1.2752x over previous
//
#include <hip/hip_runtime.h>
#include <math.h>

// HMM forward: chunked warm-start + per-step MFMA GEMM, A register-resident fp8,
// 16 waves/CU for TLP. B=32, T=2048, S=512, E=32.
// WG = one time-chunk (L=8 logged, WARM=2; chunk 0 exact pi-init). 1024 threads
// = 16 waves = 4 waves/SIMD (128 regs/wave). Each wave owns ONE 32-row n-tile
// over full K: areg = 32 i64 = 64 regs (AGPR), acc 16, working ~30 -> fits 128.
// A fp8 = 256 KB = half the CU register file; 4-way wave TLP per SIMD hides
// LDS latency / epilogue / barriers behind the shared MFMA pipe (~8 cyc/MFMA/CU).
// mfma_f32_32x32x16_fp8_fp8: D'[n][m] = sum_k A[k][n]*alpha[m][k];
// C/D col = batch m = lane&31, row n = tile*32 + 8*(reg>>2) + (reg&3) + 4*(lane>>5).
// Scaling: A x128, alpha x256, z' = 32768*z; one logf after the loop.

#define BATCH 32
#define T_LEN 2048
#define S_N   512
#define E_N   32
#define CHUNKS 256
#define L_CH  (T_LEN / CHUNKS)   // 8
#define WARM  2
#define WIN   (L_CH + WARM)      // 10
#define ASTRIDE 520              // alpha row stride in BYTES
#define SA 256.0f
#define SM 128.0f

typedef __attribute__((ext_vector_type(16))) float floatx16;
typedef __attribute__((ext_vector_type(4))) short short4v;
typedef long long i64;

__device__ __forceinline__ float bf16_to_f(short s) {
    unsigned int u = ((unsigned int)(unsigned short)s) << 16;
    return __builtin_bit_cast(float, u);
}
__device__ __forceinline__ short f_to_bf16(float f) {
    unsigned int u = __builtin_bit_cast(unsigned int, f);
    u = (u + 0x7FFFu + ((u >> 16) & 1u)) >> 16;   // RNE
    return (short)u;
}

// ---------------- prep: A^T fp8 fragments + bf16 em table (parallel) + out zero ----
// Aperm flat idx ((tile*32 + ks)*64 + lane), i64 of 8 fp8:
//   byte j = e4m3( A[ks*16 + (lane>>5)*8 + j][tile*32 + (lane&31)] * SM )
// Blocks 0..31: A k-slab ks = blockIdx. Blocks 32..63: emT chunk + out zero.
__global__ __launch_bounds__(256) void prep_kernel(
    const float* __restrict__ A, const float* __restrict__ Bem,
    i64* __restrict__ Aperm, short* __restrict__ emTg, float* __restrict__ out)
{
    __shared__ float s_A[16 * 512];   // one 16-row k-slab of A, 32 KB
    const int g = blockIdx.x, tid = threadIdx.x;
    if (g < 32) {
        const float* src = A + (size_t)g * 16 * 512;
#pragma unroll
        for (int p = 0; p < 8; ++p) {
            int idx = tid + 256 * p;
            *(float4*)&s_A[idx * 4] = *(const float4*)(src + idx * 4);
        }
        __syncthreads();
        const int lane_o = tid & 63;
        const int h = lane_o >> 5, mm = lane_o & 31;
#pragma unroll
        for (int p = 0; p < 4; ++p) {
            int tile = (tid >> 6) + 4 * p;
            int n = tile * 32 + mm;
            float f[8];
#pragma unroll
            for (int j = 0; j < 8; ++j)
                f[j] = s_A[(h * 8 + j) * 512 + n] * SM;
            int lo = __builtin_amdgcn_cvt_pk_fp8_f32(f[0], f[1], 0, 0);
            lo     = __builtin_amdgcn_cvt_pk_fp8_f32(f[2], f[3], lo, 1);
            int hi = __builtin_amdgcn_cvt_pk_fp8_f32(f[4], f[5], 0, 0);
            hi     = __builtin_amdgcn_cvt_pk_fp8_f32(f[6], f[7], hi, 1);
            Aperm[(size_t)(tile * 32 + g) * 64 + lane_o] =
                (i64)(unsigned int)lo | ((i64)(unsigned int)hi << 32);
        }
    } else {
        int base = (g - 32) * 512;
#pragma unroll
        for (int p = 0; p < 2; ++p) {
            int idx = base + tid + 256 * p;   // 0..16383 across blocks
            int e = idx >> 9, n = idx & 511;
            emTg[idx] = f_to_bf16(Bem[n * E_N + e]);
        }
        if (g == 32 && tid < 32) out[tid] = 0.0f;
    }
}

// ---------------- main kernel ----------------

__global__ __launch_bounds__(1024, 4) void hmm_kernel(
    const float* __restrict__ inputs, const i64* __restrict__ Aperm,
    const float* __restrict__ pi, const short* __restrict__ emTg,
    float* __restrict__ out)
{
    __shared__ i64   s_alpha8[BATCH * ASTRIDE / 8];   // fp8 alpha [m][k], 16.6 KB
    __shared__ float s_part[16][32];                  // per-wave z partials
    __shared__ float s_zi[32];
    __shared__ int   s_obs[BATCH * WIN];              // 320 ints
    unsigned char* s_alpha = (unsigned char*)s_alpha8;

    const int c    = blockIdx.x;
    const int tid  = threadIdx.x;      // 0..1023
    const int wv   = tid >> 6;         // wave 0..15 -> n-tile of 32 rows
    const int lane = tid & 63;
    const int h    = lane >> 5;        // half-wave
    const int m    = lane & 31;        // batch column (C/D col)

    const int t_log = c * L_CH;
    const int t_end = t_log + L_CH;
    const int t_w0  = t_end - WIN;                 // may be negative
    int t0 = t_log - 1 - WARM;
    const bool exact0 = (t0 < 0);
    const int t_begin = (t0 < 0 ? 0 : t0) + 1;

    // ---- decode obs window from one-hot (one pass: 320 entries, 1024 threads) ----
    if (tid < BATCH * WIN) {
        int mm = tid / WIN, tt = tid - mm * WIN;
        int t = t_w0 + tt;
        if (t >= 0) {
            const float* p = inputs + ((size_t)mm * T_LEN + t) * E_N;
            float o = 0.0f;
#pragma unroll
            for (int gg = 0; gg < 8; ++gg) {
                float4 v = *(const float4*)(p + gg * 4);
                o += (4 * gg) * v.x + (4 * gg + 1) * v.y + (4 * gg + 2) * v.z + (4 * gg + 3) * v.w;
            }
            s_obs[tid] = (int)(o + 0.5f);
        }
    }
    __syncthreads();

    float logacc = 0.0f;   // tid < 32
    float zprod  = 1.0f;

    if (exact0) {
        // exact init (c==0 only): thread tid<512 owns state j=tid
        if (tid < 512) {
            const int dt0 = -t_w0;
            float pj = pi[tid];
            for (int mm = 0; mm < 32; ++mm) {
                int o = s_obs[mm * WIN + dt0];
                float v = pj * bf16_to_f(emTg[o * S_N + tid]);
                v += __shfl_xor(v, 1);  v += __shfl_xor(v, 2);  v += __shfl_xor(v, 4);
                v += __shfl_xor(v, 8);  v += __shfl_xor(v, 16); v += __shfl_xor(v, 32);
                if (lane == 0) s_part[wv][mm] = v;   // wv < 8 here
            }
        }
        __syncthreads();
        if (tid < 32) {
            float z = 0.0f;
#pragma unroll
            for (int w2 = 0; w2 < 8; ++w2) z += s_part[w2][tid];
            logacc += logf(z);                    // z0
            s_zi[tid] = SA / z;
        }
        __syncthreads();
        if (tid < 512) {
            const int dt0 = -t_w0;
            float pj = pi[tid];
            for (int mm = 0; mm < 32; ++mm) {
                int o = s_obs[mm * WIN + dt0];
                float v = pj * bf16_to_f(emTg[o * S_N + tid]) * s_zi[mm];
                s_alpha[mm * ASTRIDE + tid] =
                    (unsigned char)(__builtin_amdgcn_cvt_pk_fp8_f32(v, 0.0f, 0, 0) & 0xff);
            }
        }
        __syncthreads();
    } else {
        // uniform warm start: alpha = 1/512 -> x256 = 0.5 -> e4m3 0x30
        const i64 u8 = 0x3030303030303030LL;
        for (int i = tid; i < BATCH * ASTRIDE / 8; i += 1024) s_alpha8[i] = u8;
        __syncthreads();
    }

    // ---- this wave's A^T tile: 32 i64 = 64 regs, loaded once (after init frees regs) ----
    i64 areg[32];   // [ks]
#pragma unroll
    for (int i = 0; i < 32; ++i)
        areg[i] = Aperm[(size_t)(wv * 32 + i) * 64 + lane];

    // ---------------- time loop ----------------
    for (int t = t_begin; t < t_end; ++t) {
        const int dtw = t - t_w0;
        const int o = s_obs[m * WIN + dtw];                  // batch m's symbol
        const short* emp = emTg + o * S_N + wv * 32 + h * 4;
        short4v emv[4];                                       // [g] -> n = tile+8g+4h+r
#pragma unroll
        for (int gg = 0; gg < 4; ++gg)
            emv[gg] = *(const short4v*)(emp + gg * 8);

        floatx16 acc = (floatx16)(0.0f);
#pragma unroll
        for (int ks = 0; ks < 32; ++ks) {
            i64 b = *(const i64*)(s_alpha + m * ASTRIDE + ks * 16 + h * 8);
            acc = __builtin_amdgcn_mfma_f32_32x32x16_fp8_fp8(areg[ks], b, acc, 0, 0, 0);
        }

        // emission scale + per-batch partial (16 values/lane)
        float psum = 0.0f;
#pragma unroll
        for (int reg = 0; reg < 16; ++reg) {
            float v = acc[reg] * bf16_to_f(emv[reg >> 2][reg & 3]);
            acc[reg] = v;
            psum += v;
        }
        psum += __shfl_xor(psum, 32);
        if (lane < 32) s_part[wv][m] = psum;
        __syncthreads();

        float zin = 0.0f;
#pragma unroll
        for (int w2 = 0; w2 < 16; ++w2) zin += s_part[w2][m];
        if (t >= t_log) zprod *= zin * 0x1p-15f;   // z'/32768; logf deferred
        float zi = SA / zin;

        // normalize + pack fp8 + write next alpha (4 x ds_write_b32)
#pragma unroll
        for (int gg = 0; gg < 4; ++gg) {
            int pk = __builtin_amdgcn_cvt_pk_fp8_f32(acc[gg * 4] * zi, acc[gg * 4 + 1] * zi, 0, 0);
            pk     = __builtin_amdgcn_cvt_pk_fp8_f32(acc[gg * 4 + 2] * zi, acc[gg * 4 + 3] * zi, pk, 1);
            *(int*)(s_alpha + m * ASTRIDE + wv * 32 + gg * 8 + h * 4) = pk;
        }
        __syncthreads();
    }

    if (tid < 32) atomicAdd(out + tid, logacc + logf(zprod));
}

// ---------------- launch ----------------

extern "C" void kernel_launch(void* const* d_in, const int* in_sizes, int n_in,
                              void* d_out, int out_size, void* d_ws, size_t ws_size,
                              hipStream_t stream) {
    const float* inputs = (const float*)d_in[0];   // [B,T,E] one-hot fp32
    const float* A      = (const float*)d_in[1];   // [S,S]
    const float* Bem    = (const float*)d_in[2];   // [S,E]
    const float* pi     = (const float*)d_in[3];   // [S]
    float* out = (float*)d_out;                    // [B]

    // workspace: Aperm fp8 256 KB | emTg bf16 32 KB
    i64*   Aperm = (i64*)d_ws;
    short* emTg  = (short*)((char*)d_ws + 256 * 1024);

    prep_kernel<<<64, 256, 0, stream>>>(A, Bem, Aperm, emTg, out);
    hmm_kernel<<<CHUNKS, 1024, 0, stream>>>(inputs, Aperm, pi, emTg, out);
}

// Round 8
// 100.658 us; speedup vs baseline: 1.3344x; 1.0465x over previous
//
#include <hip/hip_runtime.h>
#include <math.h>

// HMM forward: chunked warm-start + per-step MFMA GEMM, A register-resident fp8,
// 16 waves/WG, ONE barrier per step via deferred normalization.
// B=32, T=2048, S=512, E=32. WG = one time-chunk (L=8 logged, WARM=2; chunk 0
// exact pi-init). 1024 threads = 16 waves = 4 waves/SIMD (128 regs/wave).
// Each wave owns one 32-row n-tile over full K: areg = 32 i64 (AGPRs).
// Deferred normalization: alpha stored UNnormalized in fp8; the scale
// f(t) = SA/zin(t) folds into the next step's emission multiply. zin(t) is read
// from s_part at loop top (overlaps the MFMA chain). Ping-pong s_alpha/s_part
// buffers make read(t) / write(t+1) race-free with a single barrier.
// Invariant: zin(t+1) = 32768*z_true(t) -> logged next iteration (+1 post-loop).
// mfma_f32_32x32x16_fp8_fp8: D'[n][m] = sum_k A[k][n]*alpha[m][k];
// C/D col = batch m = lane&31, row n = tile*32 + 8*(reg>>2) + (reg&3) + 4*(lane>>5).

#define BATCH 32
#define T_LEN 2048
#define S_N   512
#define E_N   32
#define CHUNKS 256
#define L_CH  (T_LEN / CHUNKS)   // 8
#define WARM  2
#define WIN   (L_CH + WARM)      // 10
#define ASTRIDE 520              // alpha row stride in BYTES (2-way banks: free)
#define SA 256.0f
#define SM 128.0f

typedef __attribute__((ext_vector_type(16))) float floatx16;
typedef __attribute__((ext_vector_type(4))) short short4v;
typedef long long i64;

__device__ __forceinline__ float bf16_to_f(short s) {
    unsigned int u = ((unsigned int)(unsigned short)s) << 16;
    return __builtin_bit_cast(float, u);
}
__device__ __forceinline__ short f_to_bf16(float f) {
    unsigned int u = __builtin_bit_cast(unsigned int, f);
    u = (u + 0x7FFFu + ((u >> 16) & 1u)) >> 16;   // RNE
    return (short)u;
}

// ---------------- prep: A^T fp8 fragments + bf16 em table + out zero ----------------
// Aperm flat idx ((tile*32 + ks)*64 + lane), i64 of 8 fp8:
//   byte j = e4m3( A[ks*16 + (lane>>5)*8 + j][tile*32 + (lane&31)] * SM )
__global__ __launch_bounds__(256) void prep_kernel(
    const float* __restrict__ A, const float* __restrict__ Bem,
    i64* __restrict__ Aperm, short* __restrict__ emTg, float* __restrict__ out)
{
    __shared__ float s_A[16 * 512];   // one 16-row k-slab of A, 32 KB
    const int g = blockIdx.x, tid = threadIdx.x;
    if (g < 32) {
        const float* src = A + (size_t)g * 16 * 512;
#pragma unroll
        for (int p = 0; p < 8; ++p) {
            int idx = tid + 256 * p;
            *(float4*)&s_A[idx * 4] = *(const float4*)(src + idx * 4);
        }
        __syncthreads();
        const int lane_o = tid & 63;
        const int h = lane_o >> 5, mm = lane_o & 31;
#pragma unroll
        for (int p = 0; p < 4; ++p) {
            int tile = (tid >> 6) + 4 * p;
            int n = tile * 32 + mm;
            float f[8];
#pragma unroll
            for (int j = 0; j < 8; ++j)
                f[j] = s_A[(h * 8 + j) * 512 + n] * SM;
            int lo = __builtin_amdgcn_cvt_pk_fp8_f32(f[0], f[1], 0, 0);
            lo     = __builtin_amdgcn_cvt_pk_fp8_f32(f[2], f[3], lo, 1);
            int hi = __builtin_amdgcn_cvt_pk_fp8_f32(f[4], f[5], 0, 0);
            hi     = __builtin_amdgcn_cvt_pk_fp8_f32(f[6], f[7], hi, 1);
            Aperm[(size_t)(tile * 32 + g) * 64 + lane_o] =
                (i64)(unsigned int)lo | ((i64)(unsigned int)hi << 32);
        }
    } else {
        int base = (g - 32) * 512;
#pragma unroll
        for (int p = 0; p < 2; ++p) {
            int idx = base + tid + 256 * p;   // 0..16383 across blocks
            int e = idx >> 9, n = idx & 511;
            emTg[idx] = f_to_bf16(Bem[n * E_N + e]);
        }
        if (g == 32 && tid < 32) out[tid] = 0.0f;
    }
}

// ---------------- main kernel ----------------

__global__ __launch_bounds__(1024, 4) void hmm_kernel(
    const float* __restrict__ inputs, const i64* __restrict__ Aperm,
    const float* __restrict__ pi, const short* __restrict__ emTg,
    float* __restrict__ out)
{
    __shared__ i64   s_alpha8[2][BATCH * ASTRIDE / 8];   // ping-pong fp8 alpha, 2x16.6 KB
    __shared__ float s_part[2][16][32];                  // ping-pong z partials
    __shared__ float s_zi[32];
    __shared__ int   s_obs[BATCH * WIN];                 // 320 ints

    const int c    = blockIdx.x;
    const int tid  = threadIdx.x;      // 0..1023
    const int wv   = tid >> 6;         // wave 0..15 -> n-tile of 32 rows
    const int lane = tid & 63;
    const int h    = lane >> 5;        // half-wave
    const int m    = lane & 31;        // batch column (C/D col)

    const int t_log = c * L_CH;
    const int t_end = t_log + L_CH;
    const int t_w0  = t_end - WIN;                 // may be negative
    int t0 = t_log - 1 - WARM;
    const bool exact0 = (t0 < 0);
    const int t_begin = (t0 < 0 ? 0 : t0) + 1;
    const int pb0 = t_begin & 1;

    // ---- decode obs window from one-hot ----
    if (tid < BATCH * WIN) {
        int mm = tid / WIN, tt = tid - mm * WIN;
        int t = t_w0 + tt;
        if (t >= 0) {
            const float* p = inputs + ((size_t)mm * T_LEN + t) * E_N;
            float o = 0.0f;
#pragma unroll
            for (int gg = 0; gg < 8; ++gg) {
                float4 v = *(const float4*)(p + gg * 4);
                o += (4 * gg) * v.x + (4 * gg + 1) * v.y + (4 * gg + 2) * v.z + (4 * gg + 3) * v.w;
            }
            s_obs[tid] = (int)(o + 0.5f);
        }
    }
    // preset s_part[pb0] so zin(t_begin) = SA (alpha starts normalized*SA)
    if (tid < 512) (&s_part[pb0][0][0])[tid] = SA / 16.0f;
    if (!exact0) {
        // uniform warm start: alpha = 1/512 -> x256 = 0.5 -> e4m3 0x30
        const i64 u8 = 0x3030303030303030LL;
        for (int i = tid; i < BATCH * ASTRIDE / 8; i += 1024) s_alpha8[pb0][i] = u8;
    }
    __syncthreads();

    float logacc = 0.0f;   // tid < 32
    float zprod  = 1.0f;

    if (exact0) {
        // exact init (c==0): thread tid<512 owns state j=tid; scratch buf = 1^pb0
        unsigned char* sA0 = (unsigned char*)s_alpha8[pb0];
        if (tid < 512) {
            const int dt0 = -t_w0;
            float pj = pi[tid];
            for (int mm = 0; mm < 32; ++mm) {
                int o = s_obs[mm * WIN + dt0];
                float v = pj * bf16_to_f(emTg[o * S_N + tid]);
                v += __shfl_xor(v, 1);  v += __shfl_xor(v, 2);  v += __shfl_xor(v, 4);
                v += __shfl_xor(v, 8);  v += __shfl_xor(v, 16); v += __shfl_xor(v, 32);
                if (lane == 0) s_part[1 ^ pb0][wv][mm] = v;   // wv < 8 here
            }
        }
        __syncthreads();
        if (tid < 32) {
            float z = 0.0f;
#pragma unroll
            for (int w2 = 0; w2 < 8; ++w2) z += s_part[1 ^ pb0][w2][tid];
            logacc += logf(z);                    // z0
            s_zi[tid] = SA / z;
        }
        __syncthreads();
        if (tid < 512) {
            const int dt0 = -t_w0;
            float pj = pi[tid];
            for (int mm = 0; mm < 32; ++mm) {
                int o = s_obs[mm * WIN + dt0];
                float v = pj * bf16_to_f(emTg[o * S_N + tid]) * s_zi[mm];
                sA0[mm * ASTRIDE + tid] =
                    (unsigned char)(__builtin_amdgcn_cvt_pk_fp8_f32(v, 0.0f, 0, 0) & 0xff);
            }
        }
        __syncthreads();
    }

    // ---- this wave's A^T tile: 32 i64 = 64 regs (AGPRs), loaded once ----
    i64 areg[32];   // [ks]
#pragma unroll
    for (int i = 0; i < 32; ++i)
        areg[i] = Aperm[(size_t)(wv * 32 + i) * 64 + lane];

    // ---------------- time loop: ONE barrier per step ----------------
    for (int t = t_begin; t < t_end; ++t) {
        const int p = t & 1;
        const unsigned char* aR = (const unsigned char*)s_alpha8[p];
        unsigned char*       aW = (unsigned char*)s_alpha8[1 ^ p];

        const int dtw = t - t_w0;
        const int o = s_obs[m * WIN + dtw];                  // batch m's symbol
        const short* emp = emTg + o * S_N + wv * 32 + h * 4;
        short4v emv[4];                                       // n = tile+8g+4h+r
#pragma unroll
        for (int gg = 0; gg < 4; ++gg)
            emv[gg] = *(const short4v*)(emp + gg * 8);

        // zin = sum of current alpha_un (partials written last step) — overlaps GEMM
        float zin = 0.0f;
#pragma unroll
        for (int w2 = 0; w2 < 16; ++w2) zin += s_part[p][w2][m];

        floatx16 acc = (floatx16)(0.0f);
#pragma unroll
        for (int ks = 0; ks < 32; ++ks) {
            i64 b = *(const i64*)(aR + m * ASTRIDE + ks * 16 + h * 8);
            acc = __builtin_amdgcn_mfma_f32_32x32x16_fp8_fp8(areg[ks], b, acc, 0, 0, 0);
        }

        if (t > t_log && t > t_begin) zprod *= zin * 0x1p-15f;   // = z_true(t-1)
        const float f = SA / zin;                                 // deferred normalization

        // emission scale (x f) + per-batch partial (16 values/lane)
        float psum = 0.0f;
#pragma unroll
        for (int reg = 0; reg < 16; ++reg) {
            float v = acc[reg] * bf16_to_f(emv[reg >> 2][reg & 3]) * f;
            acc[reg] = v;
            psum += v;
        }
        psum += __shfl_xor(psum, 32);
        if (lane < 32) s_part[1 ^ p][wv][m] = psum;

        // pack fp8 + write next alpha_un (4 x ds_write_b32)
#pragma unroll
        for (int gg = 0; gg < 4; ++gg) {
            int pk = __builtin_amdgcn_cvt_pk_fp8_f32(acc[gg * 4], acc[gg * 4 + 1], 0, 0);
            pk     = __builtin_amdgcn_cvt_pk_fp8_f32(acc[gg * 4 + 2], acc[gg * 4 + 3], pk, 1);
            *(int*)(aW + m * ASTRIDE + wv * 32 + gg * 8 + h * 4) = pk;
        }
        __syncthreads();
    }

    // final z (partials of the last step live in buffer t_end&1)
    {
        float zin = 0.0f;
#pragma unroll
        for (int w2 = 0; w2 < 16; ++w2) zin += s_part[t_end & 1][w2][m];
        zprod *= zin * 0x1p-15f;
    }

    if (tid < 32) atomicAdd(out + tid, logacc + logf(zprod));
}

// ---------------- launch ----------------

extern "C" void kernel_launch(void* const* d_in, const int* in_sizes, int n_in,
                              void* d_out, int out_size, void* d_ws, size_t ws_size,
                              hipStream_t stream) {
    const float* inputs = (const float*)d_in[0];   // [B,T,E] one-hot fp32
    const float* A      = (const float*)d_in[1];   // [S,S]
    const float* Bem    = (const float*)d_in[2];   // [S,E]
    const float* pi     = (const float*)d_in[3];   // [S]
    float* out = (float*)d_out;                    // [B]

    // workspace: Aperm fp8 256 KB | emTg bf16 32 KB
    i64*   Aperm = (i64*)d_ws;
    short* emTg  = (short*)((char*)d_ws + 256 * 1024);

    prep_kernel<<<64, 256, 0, stream>>>(A, Bem, Aperm, emTg, out);
    hmm_kernel<<<CHUNKS, 1024, 0, stream>>>(inputs, Aperm, pi, emTg, out);
}